// Round 3
// baseline (154.714 us; speedup 1.0000x reference)
//
#include <hip/hip_runtime.h>

#define NROWS 4096
#define DDIM  256
#define MARGIN 0.1f
#define GX 32
#define GY 32
#define NBLOCKS (GX * GY)

typedef __attribute__((ext_vector_type(4)))  _Float16 half4;
typedef __attribute__((ext_vector_type(8)))  _Float16 half8;
typedef __attribute__((ext_vector_type(16))) float    floatx16;

// ---------------- Kernel A: diag + fp16 hi/lo split + zero rank ----------------
// hi=(f16)x, lo=(f16)(x-hi), RNE both — numerics identical to prior rounds.
__global__ __launch_bounds__(256) void prep_kernel(
    const float* __restrict__ v, const float* __restrict__ t,
    float* __restrict__ diag, int* __restrict__ rank,
    _Float16* __restrict__ vhi, _Float16* __restrict__ vlo,
    _Float16* __restrict__ thi, _Float16* __restrict__ tlo) {
  const int wv   = threadIdx.x >> 6;
  const int lane = threadIdx.x & 63;
  const int row  = blockIdx.x * 4 + wv;
  const float4 a = ((const float4*)(v + (size_t)row * DDIM))[lane];
  const float4 b = ((const float4*)(t + (size_t)row * DDIM))[lane];

  half4 ah, al, bh, bl;
  ah.x = (_Float16)a.x; al.x = (_Float16)(a.x - (float)ah.x);
  ah.y = (_Float16)a.y; al.y = (_Float16)(a.y - (float)ah.y);
  ah.z = (_Float16)a.z; al.z = (_Float16)(a.z - (float)ah.z);
  ah.w = (_Float16)a.w; al.w = (_Float16)(a.w - (float)ah.w);
  bh.x = (_Float16)b.x; bl.x = (_Float16)(b.x - (float)bh.x);
  bh.y = (_Float16)b.y; bl.y = (_Float16)(b.y - (float)bh.y);
  bh.z = (_Float16)b.z; bl.z = (_Float16)(b.z - (float)bh.z);
  bh.w = (_Float16)b.w; bl.w = (_Float16)(b.w - (float)bh.w);

  const size_t o = (size_t)row * DDIM + lane * 4;
  *(half4*)(vhi + o) = ah;
  *(half4*)(vlo + o) = al;
  *(half4*)(thi + o) = bh;
  *(half4*)(tlo + o) = bl;

  float s = a.x*b.x + a.y*b.y + a.z*b.z + a.w*b.w;
  #pragma unroll
  for (int off = 32; off; off >>= 1) s += __shfl_down(s, off);
  if (lane == 0) { diag[row] = s; rank[row] = 0; }
}

// ---------------- Kernel B: register-direct MFMA GEMM + epilogue ----------------
// 128x128 block tile, 4 waves of 64x64, NO LDS staging, NO hot-loop barriers.
// A/B fragments for mfma_32x32x16_f16 are 8 contiguous halves (16B) in the
// row-major fp16 planes -> loaded straight from global (L2-resident) into
// registers, 1-deep double-buffered. Waves 0,1 share A addrs; 0,2 share B
// addrs -> L1 dedup. Per-acc k order and term order (al*bh, ah*bl, ah*bh)
// identical to prior rounds -> bit-identical results.
__global__ __launch_bounds__(256) void main_kernel(
    const _Float16* __restrict__ vhi, const _Float16* __restrict__ vlo,
    const _Float16* __restrict__ thi, const _Float16* __restrict__ tlo,
    const float* __restrict__ diag, float* __restrict__ pvt,
    float* __restrict__ ptv, int* __restrict__ rank) {
  __shared__ float sdi[128];
  __shared__ float sdj[128];
  __shared__ float red[8];

  const int tid  = threadIdx.x;
  const int w    = tid >> 6;
  const int lane = tid & 63;
  const int i0   = blockIdx.y * 128;
  const int j0   = blockIdx.x * 128;

  if (tid < 128) sdi[tid] = diag[i0 + tid];
  else           sdj[tid - 128] = diag[j0 + tid - 128];

  const int mrow = lane & 31;
  const int hsel = lane >> 5;
  const size_t aoff = (size_t)(i0 + (w >> 1) * 64 + mrow) * DDIM + hsel * 8;
  const size_t boff = (size_t)(j0 + (w & 1) * 64 + mrow) * DDIM + hsel * 8;

  const _Float16* pAh0 = vhi + aoff;  const _Float16* pAh1 = vhi + aoff + 32 * DDIM;
  const _Float16* pAl0 = vlo + aoff;  const _Float16* pAl1 = vlo + aoff + 32 * DDIM;
  const _Float16* pBh0 = thi + boff;  const _Float16* pBh1 = thi + boff + 32 * DDIM;
  const _Float16* pBl0 = tlo + boff;  const _Float16* pBl1 = tlo + boff + 32 * DDIM;

  floatx16 acc[2][2];
  #pragma unroll
  for (int mt = 0; mt < 2; ++mt)
    #pragma unroll
    for (int nt = 0; nt < 2; ++nt)
      #pragma unroll
      for (int r = 0; r < 16; ++r) acc[mt][nt][r] = 0.f;

  half8 A0h[2], A0l[2], B0h[2], B0l[2];
  half8 A1h[2], A1l[2], B1h[2], B1l[2];

  // prologue: kstep 0 into F0
  A0h[0] = *(const half8*)(pAh0); A0h[1] = *(const half8*)(pAh1);
  A0l[0] = *(const half8*)(pAl0); A0l[1] = *(const half8*)(pAl1);
  B0h[0] = *(const half8*)(pBh0); B0h[1] = *(const half8*)(pBh1);
  B0l[0] = *(const half8*)(pBl0); B0l[1] = *(const half8*)(pBl1);

  // 12 MFMAs per kstep: term-outer across the 4 independent acc tiles
  // (per-element accumulation order unchanged: al*bh, ah*bl, ah*bh).
#define MFMA_SET(Ah, Al, Bh, Bl)                                                      \
  {                                                                                   \
    _Pragma("unroll") for (int mt = 0; mt < 2; ++mt)                                  \
      _Pragma("unroll") for (int nt = 0; nt < 2; ++nt)                                \
        acc[mt][nt] = __builtin_amdgcn_mfma_f32_32x32x16_f16(Al[mt], Bh[nt], acc[mt][nt], 0, 0, 0); \
    _Pragma("unroll") for (int mt = 0; mt < 2; ++mt)                                  \
      _Pragma("unroll") for (int nt = 0; nt < 2; ++nt)                                \
        acc[mt][nt] = __builtin_amdgcn_mfma_f32_32x32x16_f16(Ah[mt], Bl[nt], acc[mt][nt], 0, 0, 0); \
    _Pragma("unroll") for (int mt = 0; mt < 2; ++mt)                                  \
      _Pragma("unroll") for (int nt = 0; nt < 2; ++nt)                                \
        acc[mt][nt] = __builtin_amdgcn_mfma_f32_32x32x16_f16(Ah[mt], Bh[nt], acc[mt][nt], 0, 0, 0); \
  }

  #pragma unroll 1
  for (int s = 0; s < 8; ++s) {
    // issue kstep 2s+1 into F1 (+16 halves = +32B, folds as imm offset)
    A1h[0] = *(const half8*)(pAh0 + 16); A1h[1] = *(const half8*)(pAh1 + 16);
    A1l[0] = *(const half8*)(pAl0 + 16); A1l[1] = *(const half8*)(pAl1 + 16);
    B1h[0] = *(const half8*)(pBh0 + 16); B1h[1] = *(const half8*)(pBh1 + 16);
    B1l[0] = *(const half8*)(pBl0 + 16); B1l[1] = *(const half8*)(pBl1 + 16);

    // compute kstep 2s
    MFMA_SET(A0h, A0l, B0h, B0l);

    if (s < 7) {
      // issue kstep 2s+2 into F0 (+32 halves = +64B)
      A0h[0] = *(const half8*)(pAh0 + 32); A0h[1] = *(const half8*)(pAh1 + 32);
      A0l[0] = *(const half8*)(pAl0 + 32); A0l[1] = *(const half8*)(pAl1 + 32);
      B0h[0] = *(const half8*)(pBh0 + 32); B0h[1] = *(const half8*)(pBh1 + 32);
      B0l[0] = *(const half8*)(pBl0 + 32); B0l[1] = *(const half8*)(pBl1 + 32);
    }

    // compute kstep 2s+1
    MFMA_SET(A1h, A1l, B1h, B1l);

    pAh0 += 32; pAh1 += 32; pAl0 += 32; pAl1 += 32;
    pBh0 += 32; pBh1 += 32; pBl0 += 32; pBl1 += 32;
  }

  __syncthreads();   // sdi/sdj visible to all waves

  // ---- epilogue: C/D layout col=lane&31, row=(reg&3)+8*(reg>>2)+4*(lane>>5) ----
  float vt = 0.f, tv = 0.f;
  const int colL = lane & 31;
  #pragma unroll
  for (int mt = 0; mt < 2; ++mt) {
    const int rbase = (w >> 1) * 64 + mt * 32;
    #pragma unroll
    for (int reg = 0; reg < 16; ++reg) {
      const int r  = (reg & 3) + 8 * (reg >> 2) + 4 * hsel;
      const int gi = i0 + rbase + r;
      const float di = sdi[rbase + r];
      unsigned long long b0 = 0, b1 = 0;
      #pragma unroll
      for (int nt = 0; nt < 2; ++nt) {
        const int c2 = (w & 1) * 64 + nt * 32 + colL;
        const int gj = j0 + c2;
        const float sc = acc[mt][nt][reg];
        const float dj = sdj[c2];
        const bool ne = (gi != gj);
        if (ne) {
          vt += fmaxf(0.f, MARGIN - di + sc);
          tv += fmaxf(0.f, MARGIN - dj + sc);
        }
        const unsigned long long bb = __ballot(ne && (sc > di));
        if (nt == 0) b0 = bb; else b1 = bb;
      }
      if (colL == 0) {
        const int cc = hsel ? (int)(__popcll(b0 >> 32) + __popcll(b1 >> 32))
                            : (int)(__popcll(b0 & 0xFFFFFFFFull) + __popcll(b1 & 0xFFFFFFFFull));
        atomicAdd(&rank[gi], cc);
      }
    }
  }
  #pragma unroll
  for (int off = 32; off; off >>= 1) {
    vt += __shfl_down(vt, off);
    tv += __shfl_down(tv, off);
  }
  if (lane == 0) { red[w] = vt; red[4 + w] = tv; }
  __syncthreads();
  if (tid == 0) {
    const int bid = blockIdx.y * GX + blockIdx.x;
    pvt[bid] = red[0] + red[1] + red[2] + red[3];
    ptv[bid] = red[4] + red[5] + red[6] + red[7];
  }
}

// ---------------- Kernel C: final reduction -> 6 outputs ----------------
__global__ __launch_bounds__(256) void final_kernel(
    const float* __restrict__ pvt, const float* __restrict__ ptv,
    const int* __restrict__ rank, float* __restrict__ out) {
  __shared__ int s1[4], s5[4], s10[4], ssum[4];
  __shared__ float sv[4], st[4];
  const int tid = threadIdx.x;
  int c1 = 0, c5 = 0, c10 = 0, cs = 0;
  for (int i = tid; i < NROWS; i += 256) {
    const int r = rank[i];
    c1  += (r < 1);
    c5  += (r < 5);
    c10 += (r < 10);
    cs  += r;
  }
  float fv = 0.f, ft = 0.f;
  for (int i = tid; i < NBLOCKS; i += 256) { fv += pvt[i]; ft += ptv[i]; }
  #pragma unroll
  for (int off = 32; off; off >>= 1) {
    c1  += __shfl_down(c1, off);
    c5  += __shfl_down(c5, off);
    c10 += __shfl_down(c10, off);
    cs  += __shfl_down(cs, off);
    fv  += __shfl_down(fv, off);
    ft  += __shfl_down(ft, off);
  }
  const int w = tid >> 6;
  if ((tid & 63) == 0) { s1[w] = c1; s5[w] = c5; s10[w] = c10; ssum[w] = cs; sv[w] = fv; st[w] = ft; }
  __syncthreads();
  if (tid == 0) {
    int a1 = 0, a5 = 0, a10 = 0, as = 0; float av = 0.f, at = 0.f;
    for (int k = 0; k < 4; ++k) {
      a1 += s1[k]; a5 += s5[k]; a10 += s10[k]; as += ssum[k];
      av += sv[k]; at += st[k];
    }
    const float denom = 4096.0f * 4095.0f;
    out[0] = av / denom;
    out[1] = at / denom;
    out[2] = a1  / 4096.0f;
    out[3] = a5  / 4096.0f;
    out[4] = a10 / 4096.0f;
    out[5] = (float)as / 4096.0f;
  }
}

extern "C" void kernel_launch(void* const* d_in, const int* in_sizes, int n_in,
                              void* d_out, int out_size, void* d_ws, size_t ws_size,
                              hipStream_t stream) {
  const float* v = (const float*)d_in[0];
  const float* t = (const float*)d_in[1];
  float* out = (float*)d_out;

  char* ws = (char*)d_ws;
  float* diag = (float*)(ws);                       // 16 KB
  int*   rank = (int*)(ws + (16 << 10));            // 16 KB
  float* pvt  = (float*)(ws + (32 << 10));          // 4 KB
  float* ptv  = (float*)(ws + (36 << 10));          // 4 KB
  const size_t PLANE = (size_t)NROWS * DDIM * sizeof(_Float16);  // 2 MB
  _Float16* vhi = (_Float16*)(ws + (64 << 10));
  _Float16* vlo = (_Float16*)(ws + (64 << 10) + PLANE);
  _Float16* thi = (_Float16*)(ws + (64 << 10) + 2 * PLANE);
  _Float16* tlo = (_Float16*)(ws + (64 << 10) + 3 * PLANE);

  hipLaunchKernelGGL(prep_kernel, dim3(NROWS / 4), dim3(256), 0, stream,
                     v, t, diag, rank, vhi, vlo, thi, tlo);
  hipLaunchKernelGGL(main_kernel, dim3(GX, GY), dim3(256), 0, stream,
                     vhi, vlo, thi, tlo, diag, pvt, ptv, rank);
  hipLaunchKernelGGL(final_kernel, dim3(1), dim3(256), 0, stream, pvt, ptv, rank, out);
}

// Round 4
// 114.996 us; speedup vs baseline: 1.3454x; 1.3454x over previous
//
#include <hip/hip_runtime.h>

#define NROWS 4096
#define DDIM  256
#define MARGIN 0.1f
#define GX 32
#define GY 32
#define NBLOCKS (GX * GY)
#define CHUNK_H ((size_t)NROWS * 8)   // halves per 8-col chunk (64 KB)

typedef __attribute__((ext_vector_type(4)))  _Float16 half4;
typedef __attribute__((ext_vector_type(8)))  _Float16 half8;
typedef __attribute__((ext_vector_type(16))) float    floatx16;

// ---------------- Kernel A: diag + packed fp16 hi/lo planes + zero rank ----
// hi=(f16)x, lo=(f16)(x-hi), RNE both — numerics identical to prior rounds.
// Packed fragment-major layout: element (row,k) lives at
//   ((k>>3)*NROWS + row)*8 + (k&7)
// so a 16B block = one MFMA fragment slice; staging reads are contiguous and
// LDS fragment reads are conflict-free with a LINEAR (unswizzled) LDS tile.
__global__ __launch_bounds__(256) void prep_kernel(
    const float* __restrict__ v, const float* __restrict__ t,
    float* __restrict__ diag, int* __restrict__ rank,
    _Float16* __restrict__ vhp, _Float16* __restrict__ vlp,
    _Float16* __restrict__ thp, _Float16* __restrict__ tlp) {
  const int wv   = threadIdx.x >> 6;
  const int lane = threadIdx.x & 63;
  const int row  = blockIdx.x * 4 + wv;
  const float4 a = ((const float4*)(v + (size_t)row * DDIM))[lane];
  const float4 b = ((const float4*)(t + (size_t)row * DDIM))[lane];

  half4 ah, al, bh, bl;
  ah.x = (_Float16)a.x; al.x = (_Float16)(a.x - (float)ah.x);
  ah.y = (_Float16)a.y; al.y = (_Float16)(a.y - (float)ah.y);
  ah.z = (_Float16)a.z; al.z = (_Float16)(a.z - (float)ah.z);
  ah.w = (_Float16)a.w; al.w = (_Float16)(a.w - (float)ah.w);
  bh.x = (_Float16)b.x; bl.x = (_Float16)(b.x - (float)bh.x);
  bh.y = (_Float16)b.y; bl.y = (_Float16)(b.y - (float)bh.y);
  bh.z = (_Float16)b.z; bl.z = (_Float16)(b.z - (float)bh.z);
  bh.w = (_Float16)b.w; bl.w = (_Float16)(b.w - (float)bh.w);

  // k = lane*4 .. lane*4+3 -> chunk = lane>>1, within-chunk = (lane&1)*4
  const size_t po = ((size_t)(lane >> 1) * NROWS + row) * 8 + (lane & 1) * 4;
  *(half4*)(vhp + po) = ah;
  *(half4*)(vlp + po) = al;
  *(half4*)(thp + po) = bh;
  *(half4*)(tlp + po) = bl;

  float s = a.x*b.x + a.y*b.y + a.z*b.z + a.w*b.w;
  #pragma unroll
  for (int off = 32; off; off >>= 1) s += __shfl_down(s, off);
  if (lane == 0) { diag[row] = s; rank[row] = 0; }
}

// async global->LDS, 16B per lane, linear LDS dest (wave base + lane*16)
#define GLOAD16(gp, lp) \
  __builtin_amdgcn_global_load_lds( \
      (const __attribute__((address_space(1))) unsigned int*)(gp), \
      (__attribute__((address_space(3))) unsigned int*)(lp), 16, 0, 0)

// ---------------- Kernel B: LDS-staged MFMA GEMM + epilogue ----------------
// 128x128 block tile, 4 waves of 64x64, slab = 1 kstep (K=16, hi+lo = 16 KB).
// Double-buffered (32 KB total -> 4 blocks/CU) with counted vmcnt(4): next
// slab's 4 global_load_lds stay in flight across the whole compute phase.
// Fragment-major LDS layout: per slab buffer, 4 chunks x 128 rows x 16B,
// chunk q in {hi-s0, hi-s1, lo-s0, lo-s1}. Fragment ds_read_b128 = 32
// consecutive rows x 16B contiguous per half-wave -> zero bank conflicts.
// Term order per acc element: al*bh, ah*bl, ah*bh; k ascending -> numerics
// bit-identical to prior rounds.
__global__ __launch_bounds__(256, 4) void main_kernel(
    const _Float16* __restrict__ vhp, const _Float16* __restrict__ vlp,
    const _Float16* __restrict__ thp, const _Float16* __restrict__ tlp,
    const float* __restrict__ diag, float* __restrict__ pvt,
    float* __restrict__ ptv, int* __restrict__ rank) {
  __shared__ __align__(16) _Float16 Ab[2][4096];
  __shared__ __align__(16) _Float16 Bb[2][4096];
  __shared__ float sdi[128];
  __shared__ float sdj[128];
  __shared__ float red[8];

  const int tid  = threadIdx.x;
  const int w    = tid >> 6;
  const int lane = tid & 63;

  // bijective XCD chunking (1024 % 8 == 0): each XCD gets 128 consecutive
  // wgs = 4 full A-panel rows -> A panels L2-resident per XCD.
  const int bid = blockIdx.x;
  const int wg  = (bid & 7) * (NBLOCKS / 8) + (bid >> 3);
  const int i0  = (wg >> 5) * 128;   // blockIdx.y * 128
  const int j0  = (wg & 31) * 128;   // blockIdx.x * 128

  if (tid < 128) sdi[tid] = diag[i0 + tid];
  else           sdj[tid - 128] = diag[j0 + tid - 128];
  __syncthreads();   // drains diag loads before counted-vmcnt loop begins

  // staging map: thread tid -> chunk-pair half (tid>>7), row tid&127;
  // source contiguous 16B blocks, LDS dest linear at tid*16B.
  const int srow   = tid & 127;
  const int schunk = tid >> 7;    // 0 or 1
  const size_t sbA = ((size_t)schunk * NROWS + i0 + srow) * 8;
  const size_t sbB = ((size_t)schunk * NROWS + j0 + srow) * 8;
  const _Float16* aH = vhp + sbA;
  const _Float16* aL = vlp + sbA;
  const _Float16* bH = thp + sbB;
  const _Float16* bL = tlp + sbB;
  const int dst = tid * 8;        // halves

#define STAGE(CUR, OFF) do { \
    GLOAD16(aH + (OFF), &Ab[CUR][dst]); \
    GLOAD16(aL + (OFF), &Ab[CUR][2048 + dst]); \
    GLOAD16(bH + (OFF), &Bb[CUR][dst]); \
    GLOAD16(bL + (OFF), &Bb[CUR][2048 + dst]); \
  } while (0)

  floatx16 acc[2][2];
  #pragma unroll
  for (int mt = 0; mt < 2; ++mt)
    #pragma unroll
    for (int nt = 0; nt < 2; ++nt)
      #pragma unroll
      for (int r = 0; r < 16; ++r) acc[mt][nt][r] = 0.f;

  const int hsel  = lane >> 5;
  const int hoff  = hsel * 1024;                 // chunk-s offset (halves)
  const int arow0 = (w >> 1) * 64 + (lane & 31); // + mt*32
  const int brow0 = (w & 1) * 64 + (lane & 31);  // + nt*32

  // 12 MFMAs: term-outer across 4 independent tiles; per-element order
  // al*bh, ah*bl, ah*bh (unchanged).
#define MFMA_SET(Ah, Al, Bh, Bl)                                                      \
  {                                                                                   \
    _Pragma("unroll") for (int mt = 0; mt < 2; ++mt)                                  \
      _Pragma("unroll") for (int nt = 0; nt < 2; ++nt)                                \
        acc[mt][nt] = __builtin_amdgcn_mfma_f32_32x32x16_f16(Al[mt], Bh[nt], acc[mt][nt], 0, 0, 0); \
    _Pragma("unroll") for (int mt = 0; mt < 2; ++mt)                                  \
      _Pragma("unroll") for (int nt = 0; nt < 2; ++nt)                                \
        acc[mt][nt] = __builtin_amdgcn_mfma_f32_32x32x16_f16(Ah[mt], Bl[nt], acc[mt][nt], 0, 0, 0); \
    _Pragma("unroll") for (int mt = 0; mt < 2; ++mt)                                  \
      _Pragma("unroll") for (int nt = 0; nt < 2; ++nt)                                \
        acc[mt][nt] = __builtin_amdgcn_mfma_f32_32x32x16_f16(Ah[mt], Bh[nt], acc[mt][nt], 0, 0, 0); \
  }

#define COMPUTE(CUR) do {                                                   \
    const _Float16* Ap = &Ab[CUR][0];                                       \
    const _Float16* Bp = &Bb[CUR][0];                                       \
    half8 xah[2], xal[2], xbh[2], xbl[2];                                   \
    _Pragma("unroll") for (int mt = 0; mt < 2; ++mt) {                      \
      xah[mt] = *(const half8*)(Ap + hoff + (arow0 + mt * 32) * 8);         \
      xal[mt] = *(const half8*)(Ap + 2048 + hoff + (arow0 + mt * 32) * 8);  \
    }                                                                       \
    _Pragma("unroll") for (int nt = 0; nt < 2; ++nt) {                      \
      xbh[nt] = *(const half8*)(Bp + hoff + (brow0 + nt * 32) * 8);         \
      xbl[nt] = *(const half8*)(Bp + 2048 + hoff + (brow0 + nt * 32) * 8);  \
    }                                                                       \
    __builtin_amdgcn_s_setprio(1);                                         \
    MFMA_SET(xah, xal, xbh, xbl);                                          \
    __builtin_amdgcn_s_setprio(0);                                         \
  } while (0)

  // BODY: wait cur slab (keep next in flight) -> barrier -> compute ->
  // barrier (all waves done reading buf) -> stage slab t+2 into same buf.
#define BODY(T, CUR, N, DOSTAGE) do {                                       \
    __builtin_amdgcn_sched_barrier(0);                                      \
    asm volatile("s_waitcnt vmcnt(" #N ")" ::: "memory");                   \
    __builtin_amdgcn_sched_barrier(0);                                      \
    __builtin_amdgcn_s_barrier();                                           \
    __builtin_amdgcn_sched_barrier(0);                                      \
    COMPUTE(CUR);                                                           \
    __builtin_amdgcn_sched_barrier(0);                                      \
    __builtin_amdgcn_s_barrier();                                           \
    __builtin_amdgcn_sched_barrier(0);                                      \
    if (DOSTAGE) { STAGE(CUR, (size_t)((T) + 2) * 2 * CHUNK_H); }           \
  } while (0)

  // prologue: slabs 0,1 in flight (8 vmem ops/thread)
  STAGE(0, 0);
  STAGE(1, 2 * CHUNK_H);

  #pragma unroll 1
  for (int tt = 0; tt < 7; ++tt) {
    const int t0 = 2 * tt;
    BODY(t0,     0, 4, true);
    BODY(t0 + 1, 1, 4, true);
  }
  BODY(14, 0, 4, false);
  BODY(15, 1, 0, false);

  // ---- epilogue: C/D layout col=lane&31, row=(reg&3)+8*(reg>>2)+4*(lane>>5) ----
  float vt = 0.f, tv = 0.f;
  const int colL = lane & 31;
  #pragma unroll
  for (int mt = 0; mt < 2; ++mt) {
    const int rbase = (w >> 1) * 64 + mt * 32;
    #pragma unroll
    for (int reg = 0; reg < 16; ++reg) {
      const int r  = (reg & 3) + 8 * (reg >> 2) + 4 * hsel;
      const int gi = i0 + rbase + r;
      const float di = sdi[rbase + r];
      unsigned long long b0 = 0, b1 = 0;
      #pragma unroll
      for (int nt = 0; nt < 2; ++nt) {
        const int c2 = (w & 1) * 64 + nt * 32 + colL;
        const int gj = j0 + c2;
        const float sc = acc[mt][nt][reg];
        const float dj = sdj[c2];
        const bool ne = (gi != gj);
        if (ne) {
          vt += fmaxf(0.f, MARGIN - di + sc);
          tv += fmaxf(0.f, MARGIN - dj + sc);
        }
        const unsigned long long bb = __ballot(ne && (sc > di));
        if (nt == 0) b0 = bb; else b1 = bb;
      }
      if (colL == 0) {
        const int cc = hsel ? (int)(__popcll(b0 >> 32) + __popcll(b1 >> 32))
                            : (int)(__popcll(b0 & 0xFFFFFFFFull) + __popcll(b1 & 0xFFFFFFFFull));
        atomicAdd(&rank[gi], cc);
      }
    }
  }
  #pragma unroll
  for (int off = 32; off; off >>= 1) {
    vt += __shfl_down(vt, off);
    tv += __shfl_down(tv, off);
  }
  if (lane == 0) { red[w] = vt; red[4 + w] = tv; }
  __syncthreads();
  if (tid == 0) {
    pvt[wg] = red[0] + red[1] + red[2] + red[3];
    ptv[wg] = red[4] + red[5] + red[6] + red[7];
  }
}

// ---------------- Kernel C: final reduction -> 6 outputs ----------------
__global__ __launch_bounds__(256) void final_kernel(
    const float* __restrict__ pvt, const float* __restrict__ ptv,
    const int* __restrict__ rank, float* __restrict__ out) {
  __shared__ int s1[4], s5[4], s10[4], ssum[4];
  __shared__ float sv[4], st[4];
  const int tid = threadIdx.x;
  int c1 = 0, c5 = 0, c10 = 0, cs = 0;
  for (int i = tid; i < NROWS; i += 256) {
    const int r = rank[i];
    c1  += (r < 1);
    c5  += (r < 5);
    c10 += (r < 10);
    cs  += r;
  }
  float fv = 0.f, ft = 0.f;
  for (int i = tid; i < NBLOCKS; i += 256) { fv += pvt[i]; ft += ptv[i]; }
  #pragma unroll
  for (int off = 32; off; off >>= 1) {
    c1  += __shfl_down(c1, off);
    c5  += __shfl_down(c5, off);
    c10 += __shfl_down(c10, off);
    cs  += __shfl_down(cs, off);
    fv  += __shfl_down(fv, off);
    ft  += __shfl_down(ft, off);
  }
  const int w = tid >> 6;
  if ((tid & 63) == 0) { s1[w] = c1; s5[w] = c5; s10[w] = c10; ssum[w] = cs; sv[w] = fv; st[w] = ft; }
  __syncthreads();
  if (tid == 0) {
    int a1 = 0, a5 = 0, a10 = 0, as = 0; float av = 0.f, at = 0.f;
    for (int k = 0; k < 4; ++k) {
      a1 += s1[k]; a5 += s5[k]; a10 += s10[k]; as += ssum[k];
      av += sv[k]; at += st[k];
    }
    const float denom = 4096.0f * 4095.0f;
    out[0] = av / denom;
    out[1] = at / denom;
    out[2] = a1  / 4096.0f;
    out[3] = a5  / 4096.0f;
    out[4] = a10 / 4096.0f;
    out[5] = (float)as / 4096.0f;
  }
}

extern "C" void kernel_launch(void* const* d_in, const int* in_sizes, int n_in,
                              void* d_out, int out_size, void* d_ws, size_t ws_size,
                              hipStream_t stream) {
  const float* v = (const float*)d_in[0];
  const float* t = (const float*)d_in[1];
  float* out = (float*)d_out;

  char* ws = (char*)d_ws;
  float* diag = (float*)(ws);                       // 16 KB
  int*   rank = (int*)(ws + (16 << 10));            // 16 KB
  float* pvt  = (float*)(ws + (32 << 10));          // 4 KB
  float* ptv  = (float*)(ws + (36 << 10));          // 4 KB
  const size_t PLANE = (size_t)NROWS * DDIM * sizeof(_Float16);  // 2 MB
  _Float16* vhp = (_Float16*)(ws + (64 << 10));
  _Float16* vlp = (_Float16*)(ws + (64 << 10) + PLANE);
  _Float16* thp = (_Float16*)(ws + (64 << 10) + 2 * PLANE);
  _Float16* tlp = (_Float16*)(ws + (64 << 10) + 3 * PLANE);

  hipLaunchKernelGGL(prep_kernel, dim3(NROWS / 4), dim3(256), 0, stream,
                     v, t, diag, rank, vhp, vlp, thp, tlp);
  hipLaunchKernelGGL(main_kernel, dim3(NBLOCKS), dim3(256), 0, stream,
                     vhp, vlp, thp, tlp, diag, pvt, ptv, rank);
  hipLaunchKernelGGL(final_kernel, dim3(1), dim3(256), 0, stream, pvt, ptv, rank, out);
}